// Round 1
// baseline (503.040 us; speedup 1.0000x reference)
//
#include <hip/hip_runtime.h>
#include <stdint.h>

typedef unsigned short u16;
typedef __bf16 bf16x8 __attribute__((ext_vector_type(8)));
typedef float f32x4 __attribute__((ext_vector_type(4)));
typedef unsigned short ushort8 __attribute__((ext_vector_type(8)));

#define MFMA __builtin_amdgcn_mfma_f32_16x16x32_bf16

__device__ __forceinline__ u16 f2bf(float f){
  uint32_t u = __builtin_bit_cast(uint32_t, f);
  u += 0x7fffu + ((u >> 16) & 1u);
  return (u16)(u >> 16);
}
__device__ __forceinline__ float bf2f(u16 h){
  uint32_t u = ((uint32_t)h) << 16;
  return __builtin_bit_cast(float, u);
}
__device__ __forceinline__ bf16x8 ld8(const u16* p){
  return __builtin_bit_cast(bf16x8, *(const ushort8*)p);
}
__device__ __forceinline__ void gload16(const void* g, void* l){
  __builtin_amdgcn_global_load_lds((__attribute__((address_space(1))) void*)(void*)g,
                                   (__attribute__((address_space(3))) void*)l, 16, 0, 0);
}

// ---------------- convert / transpose ----------------

__global__ __launch_bounds__(256) void k_conv8(const float* __restrict__ in, u16* __restrict__ out){
  int i = blockIdx.x*256 + threadIdx.x;   // 393216 threads, 8 elems each
  const float4* p = (const float4*)in;
  float4 a = p[i*2], b = p[i*2+1];
  ushort8 o;
  o[0]=f2bf(a.x); o[1]=f2bf(a.y); o[2]=f2bf(a.z); o[3]=f2bf(a.w);
  o[4]=f2bf(b.x); o[5]=f2bf(b.y); o[6]=f2bf(b.z); o[7]=f2bf(b.w);
  ((ushort8*)out)[i] = o;
}

// out[c][r] = in[r][c], f32 -> bf16.  grid (R/64, C/64), 256 thr
__global__ __launch_bounds__(256) void k_tr(const float* __restrict__ in, u16* __restrict__ out,
                                            int R, int Cc){
  __shared__ float tile[64][65];
  int r0 = blockIdx.x*64, c0 = blockIdx.y*64;
  int t = threadIdx.x;
  int c = t & 63, r4 = t >> 6;
  for (int i = 0; i < 16; ++i)
    tile[r4 + i*4][c] = in[(size_t)(r0 + r4 + i*4)*Cc + c0 + c];
  __syncthreads();
  for (int i = 0; i < 16; ++i){
    int rr = r4 + i*4;
    out[(size_t)(c0 + rr)*R + r0 + c] = f2bf(tile[c][rr]);
  }
}

// rel_pos tables * 8 (undo the q-prescale), bf16, padded to 128 rows
__global__ __launch_bounds__(256) void k_relconv(const float* __restrict__ rh, const float* __restrict__ rw,
                                                 u16* __restrict__ rh8, u16* __restrict__ rw8){
  int i = blockIdx.x*256 + threadIdx.x;   // 16384
  if (i < 8192)      rh8[i] = f2bf(i < 8128 ? rh[i]*8.0f : 0.0f);
  else { int j = i - 8192; rw8[j] = f2bf(j < 8128 ? rw[j]*8.0f : 0.0f); }
}

// ---------------- QKV GEMM: (4096x768)x(768x2304), split to Qs/K/Vt ----------------

__global__ __launch_bounds__(256) void k_qkv(const u16* __restrict__ X, const u16* __restrict__ WT,
                                             const float* __restrict__ bias,
                                             u16* __restrict__ Qs, u16* __restrict__ Kb, u16* __restrict__ Vt){
  __shared__ __align__(16) u16 At[128*64];
  __shared__ __align__(16) u16 Bt[128*64];
  const int tid = threadIdx.x, lane = tid & 63, w = tid >> 6;
  const int m0 = blockIdx.x*128, n0 = blockIdx.y*128;
  const int wr = (w >> 1)*64, wc = (w & 1)*64;
  const int lr = lane & 15, lg = lane >> 4;
  const int srcRow = w*32 + (lane >> 3);
  const int srcK   = (lane & 7)*8;
  f32x4 acc[4][4] = {};
  for (int kt = 0; kt < 12; ++kt){
    const int kbase = kt*64;
    for (int s = 0; s < 4; ++s){
      gload16(X  + (size_t)(m0 + srcRow + s*8)*768 + kbase + srcK, At + (w*32 + s*8)*64);
      gload16(WT + (size_t)(n0 + srcRow + s*8)*768 + kbase + srcK, Bt + (w*32 + s*8)*64);
    }
    __syncthreads();
    bf16x8 af[2][4], bfr[2][4];
    for (int ks = 0; ks < 2; ++ks)
      for (int i = 0; i < 4; ++i){
        af[ks][i]  = ld8(At + (wr + i*16 + lr)*64 + ks*32 + lg*8);
        bfr[ks][i] = ld8(Bt + (wc + i*16 + lr)*64 + ks*32 + lg*8);
      }
    for (int ks = 0; ks < 2; ++ks)
      for (int mi = 0; mi < 4; ++mi)
        for (int ni = 0; ni < 4; ++ni)
          acc[mi][ni] = MFMA(af[ks][mi], bfr[ks][ni], acc[mi][ni], 0, 0, 0);
    __syncthreads();
  }
  for (int mi = 0; mi < 4; ++mi)
    for (int ni = 0; ni < 4; ++ni){
      int col = n0 + wc + ni*16 + lr;
      int s3 = col / 768, rem = col % 768;
      int hh = rem >> 6, d = rem & 63;
      float bv = bias[col];
      for (int r = 0; r < 4; ++r){
        int row = m0 + wr + mi*16 + lg*4 + r;
        float v = acc[mi][ni][r] + bv;
        if      (s3 == 0) Qs[((size_t)hh*4096 + row)*64 + d] = f2bf(v*0.125f);
        else if (s3 == 1) Kb[((size_t)hh*4096 + row)*64 + d] = f2bf(v);
        else              Vt[((size_t)hh*64 + d)*4096 + row] = f2bf(v);
      }
    }
}

// ---------------- rel_h / rel_w via MFMA; grid (64 qh, 12 h) ----------------

__global__ __launch_bounds__(256) void k_rel(const u16* __restrict__ Qs, const u16* __restrict__ Rh8,
                                             const u16* __restrict__ Rw8,
                                             u16* __restrict__ relh, u16* __restrict__ relw){
  __shared__ __align__(16) u16 Ql[64*64];
  __shared__ __align__(16) u16 Rhl[64*64];
  __shared__ __align__(16) u16 Rwl[128*64];
  const int tid = threadIdx.x, lane = tid & 63, w = tid >> 6;
  const int qh = blockIdx.x, h = blockIdx.y;
  const int lr = lane & 15, lg = lane >> 4;
  for (int j = 0; j < 2; ++j){
    int ch = tid + 256*j;             // 0..511
    int row = ch >> 3, k8 = (ch & 7)*8;
    *(ushort8*)&Ql[row*64 + k8]  = *(const ushort8*)&Qs[((size_t)h*4096 + qh*64 + row)*64 + k8];
    *(ushort8*)&Rhl[row*64 + k8] = *(const ushort8*)&Rh8[(qh + row)*64 + k8];
  }
  for (int j = 0; j < 4; ++j){
    int ch = tid + 256*j;             // 0..1023
    int row = ch >> 3, k8 = (ch & 7)*8;
    *(ushort8*)&Rwl[row*64 + k8] = *(const ushort8*)&Rw8[row*64 + k8];
  }
  __syncthreads();
  bf16x8 a[2];
  for (int ks = 0; ks < 2; ++ks) a[ks] = ld8(Ql + (w*16 + lr)*64 + ks*32 + lg*8);
  // rel_h[qw][kh] = (Q . rel_pos_h[qh+63-kh]) ; computed as Q @ Rh[qh+c]^T, kh = 63-c
  for (int ct = 0; ct < 4; ++ct){
    f32x4 c = {};
    for (int ks = 0; ks < 2; ++ks)
      c = MFMA(a[ks], ld8(Rhl + (ct*16 + lr)*64 + ks*32 + lg*8), c, 0, 0, 0);
    int kh = 63 - (ct*16 + lr);
    for (int r = 0; r < 4; ++r){
      int qw = w*16 + lg*4 + r;
      relh[((size_t)h*4096 + qh*64 + qw)*64 + kh] = f2bf(c[r]);
    }
  }
  // rel_w[qw][kw] = (Q . rel_pos_w[qw+63-kw]) ; full band, keep valid kw
  for (int ct = 0; ct < 8; ++ct){
    f32x4 c = {};
    for (int ks = 0; ks < 2; ++ks)
      c = MFMA(a[ks], ld8(Rwl + (ct*16 + lr)*64 + ks*32 + lg*8), c, 0, 0, 0);
    int cc = ct*16 + lr;
    for (int r = 0; r < 4; ++r){
      int qw = w*16 + lg*4 + r;
      int kw = qw + 63 - cc;
      if (kw >= 0 && kw < 64)
        relw[((size_t)h*4096 + qh*64 + qw)*64 + kw] = f2bf(c[r]);
    }
  }
}

// ---------------- flash attention; grid (64 qblocks, 12 heads), 4 waves ----------------

__global__ __launch_bounds__(256) void k_flash(const u16* __restrict__ Qs, const u16* __restrict__ Kb,
                                               const u16* __restrict__ Vt,
                                               const u16* __restrict__ relh, const u16* __restrict__ relw,
                                               u16* __restrict__ Ob){
  __shared__ __align__(16) u16 Pl[4][16*64];
  const int tid = threadIdx.x, lane = tid & 63, w = tid >> 6;
  const int qb = blockIdx.x, h = blockIdx.y;
  const int lr = lane & 15, lg = lane >> 4;
  const size_t hq = (size_t)h*4096;

  bf16x8 qf[2];
  {
    int qA = qb*64 + w*16 + lr;
    qf[0] = ld8(Qs + (hq + qA)*64 + lg*8);
    qf[1] = ld8(Qs + (hq + qA)*64 + 32 + lg*8);
  }
  int qC[4];
  for (int r = 0; r < 4; ++r) qC[r] = qb*64 + w*16 + lg*4 + r;
  float rw_reg[4][4];
  for (int ct = 0; ct < 4; ++ct)
    for (int r = 0; r < 4; ++r)
      rw_reg[ct][r] = bf2f(relw[(hq + qC[r])*64 + ct*16 + lr]);

  float m[4], lsum[4] = {0.f, 0.f, 0.f, 0.f};
  for (int r = 0; r < 4; ++r) m[r] = -1e30f;
  f32x4 oacc[4] = {};
  char* Pb = (char*)&Pl[w][0];

  for (int kb = 0; kb < 64; ++kb){
    f32x4 s[4] = {};
    for (int ct = 0; ct < 4; ++ct){
      const u16* kp = Kb + (hq + kb*64 + ct*16 + lr)*64 + lg*8;
      s[ct] = MFMA(qf[0], ld8(kp),      s[ct], 0, 0, 0);
      s[ct] = MFMA(qf[1], ld8(kp + 32), s[ct], 0, 0, 0);
    }
    float rh_r[4];
    for (int r = 0; r < 4; ++r) rh_r[r] = bf2f(relh[(hq + qC[r])*64 + kb]);
    float pm[4];
    for (int r = 0; r < 4; ++r){
      s[0][r] += rh_r[r] + rw_reg[0][r];
      s[1][r] += rh_r[r] + rw_reg[1][r];
      s[2][r] += rh_r[r] + rw_reg[2][r];
      s[3][r] += rh_r[r] + rw_reg[3][r];
      pm[r] = fmaxf(fmaxf(s[0][r], s[1][r]), fmaxf(s[2][r], s[3][r]));
    }
    for (int msk = 1; msk < 16; msk <<= 1)
      for (int r = 0; r < 4; ++r) pm[r] = fmaxf(pm[r], __shfl_xor(pm[r], msk, 64));
    float corr[4], rs[4];
    for (int r = 0; r < 4; ++r){
      float nm = fmaxf(m[r], pm[r]);
      corr[r] = __expf(m[r] - nm);
      m[r] = nm;
      rs[r] = 0.f;
    }
    for (int ct = 0; ct < 4; ++ct)
      for (int r = 0; r < 4; ++r){
        float p = __expf(s[ct][r] - m[r]);
        s[ct][r] = p; rs[r] += p;
      }
    for (int msk = 1; msk < 16; msk <<= 1)
      for (int r = 0; r < 4; ++r) rs[r] += __shfl_xor(rs[r], msk, 64);
    for (int r = 0; r < 4; ++r) lsum[r] = lsum[r]*corr[r] + rs[r];
    for (int dt = 0; dt < 4; ++dt)
      for (int r = 0; r < 4; ++r) oacc[dt][r] *= corr[r];
    // P -> LDS (XOR-swizzled to kill 16-way bank conflict on the b128 reads)
    for (int ct = 0; ct < 4; ++ct)
      for (int r = 0; r < 4; ++r){
        int prow = lg*4 + r, pcol = ct*16 + lr;
        int off = (prow*128 + pcol*2) ^ ((prow & 7) << 4);
        *(u16*)(Pb + off) = f2bf(s[ct][r]);
      }
    bf16x8 pa[2];
    for (int ks = 0; ks < 2; ++ks){
      int off = (lr*128 + (ks*32 + lg*8)*2) ^ ((lr & 7) << 4);
      pa[ks] = __builtin_bit_cast(bf16x8, *(ushort8*)(Pb + off));
    }
    for (int dt = 0; dt < 4; ++dt){
      const u16* vp = Vt + ((size_t)h*64 + dt*16 + lr)*4096 + kb*64 + lg*8;
      oacc[dt] = MFMA(pa[0], ld8(vp),      oacc[dt], 0, 0, 0);
      oacc[dt] = MFMA(pa[1], ld8(vp + 32), oacc[dt], 0, 0, 0);
    }
  }
  for (int dt = 0; dt < 4; ++dt)
    for (int r = 0; r < 4; ++r)
      Ob[(size_t)qC[r]*768 + h*64 + dt*16 + lr] = f2bf(oacc[dt][r] * (1.0f / lsum[r]));
}

// ---------------- proj GEMM: (4096x768)x(768x768) + b -> f32 out ----------------

__global__ __launch_bounds__(256) void k_proj(const u16* __restrict__ A, const u16* __restrict__ WT,
                                              const float* __restrict__ bias, float* __restrict__ out){
  __shared__ __align__(16) u16 At[128*64];
  __shared__ __align__(16) u16 Bt[128*64];
  const int tid = threadIdx.x, lane = tid & 63, w = tid >> 6;
  const int m0 = blockIdx.x*128, n0 = blockIdx.y*128;
  const int wr = (w >> 1)*64, wc = (w & 1)*64;
  const int lr = lane & 15, lg = lane >> 4;
  const int srcRow = w*32 + (lane >> 3);
  const int srcK   = (lane & 7)*8;
  f32x4 acc[4][4] = {};
  for (int kt = 0; kt < 12; ++kt){
    const int kbase = kt*64;
    for (int s = 0; s < 4; ++s){
      gload16(A  + (size_t)(m0 + srcRow + s*8)*768 + kbase + srcK, At + (w*32 + s*8)*64);
      gload16(WT + (size_t)(n0 + srcRow + s*8)*768 + kbase + srcK, Bt + (w*32 + s*8)*64);
    }
    __syncthreads();
    bf16x8 af[2][4], bfr[2][4];
    for (int ks = 0; ks < 2; ++ks)
      for (int i = 0; i < 4; ++i){
        af[ks][i]  = ld8(At + (wr + i*16 + lr)*64 + ks*32 + lg*8);
        bfr[ks][i] = ld8(Bt + (wc + i*16 + lr)*64 + ks*32 + lg*8);
      }
    for (int ks = 0; ks < 2; ++ks)
      for (int mi = 0; mi < 4; ++mi)
        for (int ni = 0; ni < 4; ++ni)
          acc[mi][ni] = MFMA(af[ks][mi], bfr[ks][ni], acc[mi][ni], 0, 0, 0);
    __syncthreads();
  }
  for (int mi = 0; mi < 4; ++mi)
    for (int ni = 0; ni < 4; ++ni){
      int col = n0 + wc + ni*16 + lr;
      float bv = bias[col];
      for (int r = 0; r < 4; ++r){
        int row = m0 + wr + mi*16 + lg*4 + r;
        out[(size_t)row*768 + col] = acc[mi][ni][r] + bv;
      }
    }
}

// ---------------- launch ----------------

extern "C" void kernel_launch(void* const* d_in, const int* in_sizes, int n_in,
                              void* d_out, int out_size, void* d_ws, size_t ws_size,
                              hipStream_t stream){
  const float* X32   = (const float*)d_in[0];
  const float* qkvw  = (const float*)d_in[1];
  const float* qkvb  = (const float*)d_in[2];
  const float* projw = (const float*)d_in[3];
  const float* projb = (const float*)d_in[4];
  const float* rposh = (const float*)d_in[5];
  const float* rposw = (const float*)d_in[6];

  u16* Xb  = (u16*)d_ws;            // 4096*768
  u16* W1T = Xb  + 3145728;         // 2304*768
  u16* PT  = W1T + 1769472;         // 768*768
  u16* Rh8 = PT  + 589824;          // 128*64 (padded)
  u16* Rw8 = Rh8 + 8192;            // 128*64 (padded)
  u16* Qs  = Rw8 + 8192;            // 12*4096*64 (pre-scaled by 1/8)
  u16* Kb  = Qs  + 3145728;
  u16* Vt  = Kb  + 3145728;         // [12][64][4096] transposed
  u16* Rlh = Vt  + 3145728;         // [12][4096][64]
  u16* Rlw = Rlh + 3145728;         // [12][4096][64]
  u16* Ob  = Rlw + 3145728;         // [4096][768]
  float* out = (float*)d_out;

  k_conv8  <<<1536, 256, 0, stream>>>(X32, Xb);
  k_tr     <<<dim3(12, 36), 256, 0, stream>>>(qkvw, W1T, 768, 2304);
  k_tr     <<<dim3(12, 12), 256, 0, stream>>>(projw, PT, 768, 768);
  k_relconv<<<64, 256, 0, stream>>>(rposh, rposw, Rh8, Rw8);
  k_qkv    <<<dim3(32, 18), 256, 0, stream>>>(Xb, W1T, qkvb, Qs, Kb, Vt);
  k_rel    <<<dim3(64, 12), 256, 0, stream>>>(Qs, Rh8, Rw8, Rlh, Rlw);
  k_flash  <<<dim3(64, 12), 256, 0, stream>>>(Qs, Kb, Vt, Rlh, Rlw, Ob);
  k_proj   <<<dim3(32, 6), 256, 0, stream>>>(Ob, PT, projb, out);
}